// Round 1
// baseline (608.619 us; speedup 1.0000x reference)
//
#include <hip/hip_runtime.h>
#include <stdint.h>

#define TSTEPS 256
#define NB 16
#define NM (TSTEPS*NB)   // 4096

__device__ __forceinline__ uint32_t fkey(uint32_t u) {
  // order-preserving map f32 bits -> u32 (total order, -0 < +0; no NaN in data)
  return (u & 0x80000000u) ? ~u : (u | 0x80000000u);
}

// ---------------------------------------------------------------- rng table
__global__ void k_rng(float* __restrict__ rngf, uint32_t* __restrict__ rngk) {
  int i = threadIdx.x;               // 256 threads
  unsigned g = i ^ (i >> 1);         // Gray code
  double x = 0.0, sc = 0.5;
  for (int j = 0; j < 8; ++j) { if ((g >> j) & 1u) x += sc; sc *= 0.5; }
  float v = (float)(x * 2.0 - 1.0);  // exact dyadic
  rngf[i] = v;
  rngk[i] = fkey(__float_as_uint(v));
}

// ------------------------------------------------- layer-1 prefix (2 passes)
__global__ __launch_bounds__(256) void k_chunks(const int* __restrict__ x,
                                                uint16_t* __restrict__ cs) {
  int g = blockIdx.x * 256 + threadIdx.x;       // 131072
  int i = g & 1023, b = (g >> 10) & 15, c = g >> 14;
  int s = 0, t0 = c * 32;
  for (int tt = t0; tt < t0 + 32; ++tt) s += x[((size_t)tt * NB + b) * 1024 + i];
  cs[(c * NB + b) * 1024 + i] = (uint16_t)s;
}

__global__ __launch_bounds__(256) void k_prep1(const int* __restrict__ x,
                                               const uint16_t* __restrict__ cs,
                                               uint16_t* __restrict__ idx1,
                                               uint32_t* __restrict__ xm1) {
  int g = blockIdx.x * 256 + threadIdx.x;
  int i = g & 1023, b = (g >> 10) & 15, c = g >> 14;
  int cum = 0;
  for (int cc = 0; cc < c; ++cc) cum += cs[(cc * NB + b) * 1024 + i];
  int t0 = c * 32;
  for (int tt = t0; tt < t0 + 32; ++tt) {
    int m = tt * NB + b;
    int xv = x[((size_t)tt * NB + b) * 1024 + i];
    int idxv = xv ? cum : (tt - cum);
    idx1[(size_t)m * 1024 + i] = (uint16_t)(idxv | ((xv ^ 1) << 15));
    cum += xv;
    unsigned long long bal = __ballot(xv == 0);
    if ((i & 63) == 0) {
      xm1[(size_t)m * 32 + (i >> 5)]     = (uint32_t)bal;
      xm1[(size_t)m * 32 + (i >> 5) + 1] = (uint32_t)(bal >> 32);
    }
  }
}

// --------------------------------------------------- binary GEMM (count ops)
// Y[m][n] = sum_k ( (key(W[n][k]) ^ flip(m,k)) > ut(m,k) )
// ut from idx array: x=1 -> kr ; x=0 -> ~kr-1 with kw complemented (<=)
template<int KD>
__global__ __launch_bounds__(256) void k_bingemm(
    const uint16_t* __restrict__ Aidx, const uint32_t* __restrict__ Amask,
    const float* __restrict__ Wmat, const uint32_t* __restrict__ rngkey,
    uint16_t* __restrict__ Ycnt, int N)
{
  __shared__ uint32_t As[64][65];
  __shared__ uint32_t Bs[64][68];
  __shared__ uint32_t Ams[64][2];
  __shared__ uint32_t rk[256];
  const int tid = threadIdx.x;
  rk[tid] = rngkey[tid];
  const int m0 = blockIdx.x * 64;
  const int n0 = blockIdx.y * 64;
  const int tx = tid & 15;
  const int ty = tid >> 4;
  const int r  = tid >> 2;
  const int g4 = tid & 3;
  uint32_t acc[4][4] = {};
  constexpr int WPR = KD / 32;
  __syncthreads();
  for (int kt = 0; kt < KD / 64; ++kt) {
    { // stage A: 64 rows x 64 u16 -> transformed thresholds
      const uint16_t* src = Aidx + (size_t)(m0 + r) * KD + kt * 64 + g4 * 16;
      uint4 p0 = *(const uint4*)src;
      uint4 p1 = *(const uint4*)(src + 8);
      uint32_t wbuf[8] = {p0.x, p0.y, p0.z, p0.w, p1.x, p1.y, p1.z, p1.w};
      #pragma unroll
      for (int q = 0; q < 8; ++q) {
        uint32_t v0 = wbuf[q] & 0xFFFFu, v1 = wbuf[q] >> 16;
        uint32_t k0 = rk[v0 & 255u], k1 = rk[v1 & 255u];
        As[r][g4 * 16 + q * 2]     = (v0 & 0x8000u) ? (~k0 - 1u) : k0;
        As[r][g4 * 16 + q * 2 + 1] = (v1 & 0x8000u) ? (~k1 - 1u) : k1;
      }
    }
    { // stage B: rows o x 64 k, keyed, transposed into Bs[k][o]
      const float* wsrc = Wmat + (size_t)(n0 + r) * KD + kt * 64 + g4 * 16;
      #pragma unroll
      for (int q4 = 0; q4 < 4; ++q4) {
        float4 f = *(const float4*)(wsrc + q4 * 4);
        Bs[g4*16 + q4*4 + 0][r] = fkey(__float_as_uint(f.x));
        Bs[g4*16 + q4*4 + 1][r] = fkey(__float_as_uint(f.y));
        Bs[g4*16 + q4*4 + 2][r] = fkey(__float_as_uint(f.z));
        Bs[g4*16 + q4*4 + 3][r] = fkey(__float_as_uint(f.w));
      }
    }
    if (tid < 128) {
      int rr = tid >> 1, hw = tid & 1;
      Ams[rr][hw] = Amask[(size_t)(m0 + rr) * WPR + kt * 2 + hw];
    }
    __syncthreads();
    uint32_t am[4][2];
    #pragma unroll
    for (int rr = 0; rr < 4; ++rr) { am[rr][0] = Ams[ty*4+rr][0]; am[rr][1] = Ams[ty*4+rr][1]; }
    #pragma unroll 4
    for (int kk = 0; kk < 64; ++kk) {
      uint4 bq = *(const uint4*)&Bs[kk][tx * 4];
      #pragma unroll
      for (int rr = 0; rr < 4; ++rr) {
        uint32_t ut = As[ty * 4 + rr][kk];
        uint32_t mword = (kk < 32) ? am[rr][0] : am[rr][1];
        uint32_t mv = (uint32_t)((int32_t)(mword << (31 - (kk & 31))) >> 31);
        acc[rr][0] += ((bq.x ^ mv) > ut) ? 1u : 0u;
        acc[rr][1] += ((bq.y ^ mv) > ut) ? 1u : 0u;
        acc[rr][2] += ((bq.z ^ mv) > ut) ? 1u : 0u;
        acc[rr][3] += ((bq.w ^ mv) > ut) ? 1u : 0u;
      }
    }
    __syncthreads();
  }
  #pragma unroll
  for (int rr = 0; rr < 4; ++rr) {
    ushort4 v;
    v.x = (uint16_t)acc[rr][0]; v.y = (uint16_t)acc[rr][1];
    v.z = (uint16_t)acc[rr][2]; v.w = (uint16_t)acc[rr][3];
    *(ushort4*)&Ycnt[(size_t)(m0 + ty * 4 + rr) * N + n0 + tx * 4] = v;
  }
}

// --------------------------- scan (ulinear accum + ucompare) + next-layer prep
template<int NOUT>
__global__ __launch_bounds__(256) void k_scan(
    const uint16_t* __restrict__ ycnt, const float* __restrict__ bias,
    const float* __restrict__ rngf, float offset,
    uint16_t* __restrict__ idxn, uint32_t* __restrict__ xmn)
{
  __shared__ float rs[256];
  int tid = threadIdx.x;
  rs[tid] = rngf[tid];
  __syncthreads();
  int g = blockIdx.x * 256 + tid;
  int o = g & (NOUT - 1);
  int b = g / NOUT;
  float bo = bias[o];
  float in_acc = 0.f, out_acc = 0.f, c = 0.f;
  int cum = 0;
  constexpr int WPR = NOUT / 32;
  for (int t = 0; t < TSTEPS; ++t) {
    int m = t * NB + b;
    float y = (float)ycnt[(size_t)m * NOUT + o] + ((bo > rs[t]) ? 1.f : 0.f);
    in_acc += y - offset;
    float out = (in_acc > out_acc) ? 1.f : 0.f;
    out_acc += out;
    float a = (c < 0.f) ? 1.f : out;   // unary ReLU
    c += 2.f * a - 1.f;
    int xi = (int)a;
    int idxv = xi ? cum : (t - cum);
    idxn[(size_t)m * NOUT + o] = (uint16_t)(idxv | ((xi ^ 1) << 15));
    cum += xi;
    unsigned long long bal = __ballot(xi == 0);
    if ((o & 63) == 0) {
      xmn[(size_t)m * WPR + (o >> 5)]     = (uint32_t)bal;
      xmn[(size_t)m * WPR + (o >> 5) + 1] = (uint32_t)(bal >> 32);
    }
  }
}

// ------------------------------------------------------------ layer 3 (OUT=10)
__global__ __launch_bounds__(256) void k_l3(
    const uint16_t* __restrict__ idxA, const float* __restrict__ w3,
    const uint32_t* __restrict__ rngkey, uint16_t* __restrict__ y3)
{
  __shared__ uint32_t kw[10 * 260];
  __shared__ uint32_t rk[256];
  int tid = threadIdx.x;
  rk[tid] = rngkey[tid];
  for (int j = tid; j < 2560; j += 256) {
    int oo = j >> 8, ii = j & 255;
    kw[oo * 260 + ii] = fkey(__float_as_uint(w3[j]));
  }
  __syncthreads();
  int m = blockIdx.x * 16 + (tid >> 4);
  int o = tid & 15;
  int oc = (o < 10) ? o : 0;
  uint32_t acc = 0;
  const uint16_t* arow = idxA + (size_t)m * 256;
  #pragma unroll 4
  for (int i = 0; i < 256; ++i) {
    uint32_t v = arow[i];
    uint32_t kr = rk[v & 255u];
    uint32_t f = v >> 15;
    uint32_t ut = f ? (~kr - 1u) : kr;
    uint32_t mv = (uint32_t)(0 - f);
    acc += ((kw[oc * 260 + i] ^ mv) > ut) ? 1u : 0u;
  }
  if (o < 10) y3[m * 16 + o] = (uint16_t)acc;
}

// ----------------------------------------------------- layer-3 scan -> z vals
__global__ __launch_bounds__(256) void k_scan3(
    const uint16_t* __restrict__ y3, const float* __restrict__ b3,
    const float* __restrict__ pred, const float* __restrict__ rngf,
    float* __restrict__ zbuf)
{
  __shared__ float rs[256];
  int tid = threadIdx.x;
  rs[tid] = rngf[tid];
  __syncthreads();
  int b = tid >> 4, o = tid & 15;
  bool act = (o < 10);
  float bo = act ? b3[o] : 0.f;
  float pr = act ? pred[b * 10 + o] : 0.f;
  float in_acc = 0.f, out_acc = 0.f;
  for (int t = 0; t < TSTEPS; ++t) {
    int m = t * NB + b;
    float y = (float)y3[m * 16 + o] + ((bo > rs[t]) ? 1.f : 0.f);
    in_acc += y - 127.5f;
    float out = (in_acc > out_acc) ? 1.f : 0.f;
    out_acc += out;
    if (act) zbuf[m * 16 + o] = 2.f * out - 1.f - pr;
  }
}

// -------------------------------------------------------------- log_softmax
__global__ __launch_bounds__(256) void k_softmax(const float* __restrict__ zbuf,
                                                 float* __restrict__ out)
{
  int m = blockIdx.x * 256 + threadIdx.x;   // 4096
  float z[10], mx = -3e38f;
  #pragma unroll
  for (int o = 0; o < 10; ++o) { z[o] = zbuf[m * 16 + o]; mx = fmaxf(mx, z[o]); }
  float s = 0.f;
  #pragma unroll
  for (int o = 0; o < 10; ++o) s += expf(z[o] - mx);
  float ls = logf(s);
  #pragma unroll
  for (int o = 0; o < 10; ++o) out[m * 10 + o] = z[o] - mx - ls;
}

// ---------------------------------------------------------------------------
extern "C" void kernel_launch(void* const* d_in, const int* in_sizes, int n_in,
                              void* d_out, int out_size, void* d_ws, size_t ws_size,
                              hipStream_t stream) {
  (void)in_sizes; (void)n_in; (void)out_size; (void)ws_size;
  const float* w1   = (const float*)d_in[0];
  const float* b1   = (const float*)d_in[1];
  const float* w2   = (const float*)d_in[2];
  const float* b2   = (const float*)d_in[3];
  const float* w3   = (const float*)d_in[4];
  const float* b3   = (const float*)d_in[5];
  const float* pred = (const float*)d_in[6];
  const int*   x    = (const int*)d_in[7];
  float* out = (float*)d_out;
  uint8_t* W = (uint8_t*)d_ws;

  float*    rngf  = (float*)   (W + 0);          //   1 KB
  uint32_t* rngk  = (uint32_t*)(W + 1024);       //   1 KB
  uint16_t* chks  = (uint16_t*)(W + 2048);       // 256 KB
  uint16_t* idx1  = (uint16_t*)(W + 264192);     //   8 MB
  uint32_t* xm1   = (uint32_t*)(W + 8652800);    // 512 KB
  uint16_t* y1    = (uint16_t*)(W + 9177088);    //   4 MB
  uint16_t* idx2  = (uint16_t*)(W + 13371392);   //   4 MB
  uint32_t* xm2   = (uint32_t*)(W + 17565696);   // 256 KB
  uint16_t* y2    = (uint16_t*)(W + 17827840);   //   2 MB
  uint16_t* idx3  = (uint16_t*)(W + 19924992);   //   2 MB
  uint32_t* xm3   = (uint32_t*)(W + 22022144);   // 128 KB
  uint16_t* y3    = (uint16_t*)(W + 22153216);   // 128 KB
  float*    zbuf  = (float*)   (W + 22284288);   // 256 KB  -> total ~21.5 MB

  hipLaunchKernelGGL(k_rng,    dim3(1),   dim3(256), 0, stream, rngf, rngk);
  hipLaunchKernelGGL(k_chunks, dim3(512), dim3(256), 0, stream, x, chks);
  hipLaunchKernelGGL(k_prep1,  dim3(512), dim3(256), 0, stream, x, chks, idx1, xm1);
  hipLaunchKernelGGL(k_bingemm<1024>, dim3(64, 8), dim3(256), 0, stream,
                     idx1, xm1, w1, rngk, y1, 512);
  hipLaunchKernelGGL(k_scan<512>, dim3(32), dim3(256), 0, stream,
                     y1, b1, rngf, 511.5f, idx2, xm2);
  hipLaunchKernelGGL(k_bingemm<512>, dim3(64, 4), dim3(256), 0, stream,
                     idx2, xm2, w2, rngk, y2, 256);
  hipLaunchKernelGGL(k_scan<256>, dim3(16), dim3(256), 0, stream,
                     y2, b2, rngf, 255.5f, idx3, xm3);
  hipLaunchKernelGGL(k_l3,     dim3(256), dim3(256), 0, stream, idx3, w3, rngk, y3);
  hipLaunchKernelGGL(k_scan3,  dim3(1),   dim3(256), 0, stream, y3, b3, pred, rngf, zbuf);
  hipLaunchKernelGGL(k_softmax,dim3(16),  dim3(256), 0, stream, zbuf, out);
}

// Round 3
// 413.108 us; speedup vs baseline: 1.4733x; 1.4733x over previous
//
#include <hip/hip_runtime.h>
#include <stdint.h>

#define TSTEPS 256
#define NB 16
#define NM (TSTEPS*NB)   // 4096

typedef short s16x2 __attribute__((ext_vector_type(2)));

// perm(i) = bitrev8(gray(i)) : the Sobol value rng[i] = 2*perm(i)/256 - 1
__device__ __forceinline__ uint32_t perm8(int i) {
  uint32_t g = (uint32_t)(i ^ (i >> 1));
  return __brev(g) >> 24;
}

// packed compare-count step, per u16 half h:
//   tmp = t ^ f            (f = 0x0000 for x=1, 0x01FF for x=0 -> 511-t)
//   d   = u - tmp          (i16)
//   s   = d >> 15          (0 / -1 ; -1 iff tmp > u  == predicate true)
//   acc = acc - s          (+1 per true predicate)
// Written with clang packed-i16 vectors so VOP3P encodings (incl. the
// splatted shift amount) are compiler-correct.
__device__ __forceinline__ void qstep(uint32_t& acc, uint32_t t2, uint32_t f2,
                                      uint32_t u2) {
  uint32_t tf = t2 ^ f2;
  s16x2 d = __builtin_bit_cast(s16x2, u2) - __builtin_bit_cast(s16x2, tf);
  s16x2 s = d >> 15;
  acc = __builtin_bit_cast(uint32_t,
        (s16x2)(__builtin_bit_cast(s16x2, acc) - s));
}

// ---------------------------------------------------------------- rng table
__global__ void k_rng(float* __restrict__ rngf) {
  int i = threadIdx.x;               // 256 threads
  unsigned g = i ^ (i >> 1);         // Gray code
  double x = 0.0, sc = 0.5;
  for (int j = 0; j < 8; ++j) { if ((g >> j) & 1u) x += sc; sc *= 0.5; }
  rngf[i] = (float)(x * 2.0 - 1.0); // exact dyadic
}

// ----------------------------------------------------- weight -> rank (u16)
// t = #{g in [0,256) : 2g/256-1 < w}  (exact in double)
__global__ __launch_bounds__(256) void k_wrank(const float* __restrict__ w,
                                               uint16_t* __restrict__ T, int n) {
  int i = blockIdx.x * 256 + threadIdx.x;
  if (i >= n) return;
  double v = 128.0 * (double)w[i] + 128.0;
  int t = (int)ceil(v);
  if (t < 0) t = 0; if (t > 256) t = 256;
  T[i] = (uint16_t)t;
}

// ------------------------------------------------- layer-1 prefix (2 passes)
__global__ __launch_bounds__(256) void k_chunks(const int* __restrict__ x,
                                                uint16_t* __restrict__ cs) {
  int g = blockIdx.x * 256 + threadIdx.x;       // 131072
  int i = g & 1023, b = (g >> 10) & 15, c = g >> 14;
  int s = 0, t0 = c * 32;
  for (int tt = t0; tt < t0 + 32; ++tt) s += x[((size_t)tt * NB + b) * 1024 + i];
  cs[(c * NB + b) * 1024 + i] = (uint16_t)s;
}

__global__ __launch_bounds__(256) void k_prep1(const int* __restrict__ x,
                                               const uint16_t* __restrict__ cs,
                                               uint16_t* __restrict__ U1,
                                               uint32_t* __restrict__ xm1) {
  int g = blockIdx.x * 256 + threadIdx.x;
  int i = g & 1023, b = (g >> 10) & 15, c = g >> 14;
  int cum = 0;
  for (int cc = 0; cc < c; ++cc) cum += cs[(cc * NB + b) * 1024 + i];
  int t0 = c * 32;
  for (int tt = t0; tt < t0 + 32; ++tt) {
    int m = tt * NB + b;
    int xv = x[((size_t)tt * NB + b) * 1024 + i];
    int idx = xv ? cum : (tt - cum);
    uint32_t p = perm8(idx);
    U1[(size_t)m * 1024 + i] = (uint16_t)(xv ? p : (510u - p));
    cum += xv;
    unsigned long long bal = __ballot(xv == 0);
    if ((i & 63) == 0) {
      xm1[(size_t)m * 32 + (i >> 5)]     = (uint32_t)bal;
      xm1[(size_t)m * 32 + (i >> 5) + 1] = (uint32_t)(bal >> 32);
    }
  }
}

// --------------------------------------------- packed-rank binary GEMM
// Y[m][n] = sum_k pred(m,n,k); operands: U (staged u per (m,k)),
// XM (x==0 bitmask per (m,k)), T (rank per (n,k)).
template<int KD>
__global__ __launch_bounds__(256) void k_bingemm(
    const uint16_t* __restrict__ U, const uint32_t* __restrict__ XM,
    const uint16_t* __restrict__ T, uint16_t* __restrict__ Y, int N)
{
  __shared__ uint32_t Bs[32][68];   // [kpair][n]  t-pairs
  __shared__ uint32_t Us[64][36];   // [m][kpair]  u-pairs
  __shared__ uint32_t Fs[64][36];   // [m][kpair]  flip masks (0 / 0x1FF per half)
  const int tid = threadIdx.x;
  const int m0 = blockIdx.x * 64;
  const int n0 = blockIdx.y * 64;
  const int tx = tid & 15;
  const int ty = tid >> 4;
  const int r  = tid >> 2;
  const int g4 = tid & 3;
  uint32_t acc[4][4] = {};
  for (int kt = 0; kt < KD / 64; ++kt) {
    { // stage U rows (64 x 64 u16)
      const uint4* su = (const uint4*)(U + (size_t)(m0 + r) * KD + kt * 64 + g4 * 16);
      uint4 a0 = su[0], a1 = su[1];
      *(uint4*)&Us[r][g4 * 8]     = a0;
      *(uint4*)&Us[r][g4 * 8 + 4] = a1;
    }
    { // stage flip masks from x-bitmask
      uint32_t w = XM[(size_t)(m0 + r) * (KD / 32) + kt * 2 + (g4 >> 1)] >> ((g4 & 1) * 16);
      uint32_t fw[8];
      #pragma unroll
      for (int q = 0; q < 8; ++q) {
        uint32_t b2 = w >> (2 * q);
        fw[q] = ((b2 & 1u) * 0x1FFu) | (((b2 >> 1) & 1u) * 0x01FF0000u);
      }
      *(uint4*)&Fs[r][g4 * 8]     = make_uint4(fw[0], fw[1], fw[2], fw[3]);
      *(uint4*)&Fs[r][g4 * 8 + 4] = make_uint4(fw[4], fw[5], fw[6], fw[7]);
    }
    { // stage T (rank pairs), transposed into Bs[kpair][n]
      const uint4* st = (const uint4*)(T + (size_t)(n0 + r) * KD + kt * 64 + g4 * 16);
      uint4 t0 = st[0], t1 = st[1];
      uint32_t tw[8] = {t0.x, t0.y, t0.z, t0.w, t1.x, t1.y, t1.z, t1.w};
      #pragma unroll
      for (int q = 0; q < 8; ++q) Bs[g4 * 8 + q][r] = tw[q];
    }
    __syncthreads();
    #pragma unroll 8
    for (int kp = 0; kp < 32; ++kp) {
      uint4 bq = *(const uint4*)&Bs[kp][tx * 4];
      #pragma unroll
      for (int rr = 0; rr < 4; ++rr) {
        uint32_t u2 = Us[ty * 4 + rr][kp];
        uint32_t f2 = Fs[ty * 4 + rr][kp];
        qstep(acc[rr][0], bq.x, f2, u2);
        qstep(acc[rr][1], bq.y, f2, u2);
        qstep(acc[rr][2], bq.z, f2, u2);
        qstep(acc[rr][3], bq.w, f2, u2);
      }
    }
    __syncthreads();
  }
  #pragma unroll
  for (int rr = 0; rr < 4; ++rr) {
    ushort4 v;
    v.x = (uint16_t)((acc[rr][0] & 0xFFFFu) + (acc[rr][0] >> 16));
    v.y = (uint16_t)((acc[rr][1] & 0xFFFFu) + (acc[rr][1] >> 16));
    v.z = (uint16_t)((acc[rr][2] & 0xFFFFu) + (acc[rr][2] >> 16));
    v.w = (uint16_t)((acc[rr][3] & 0xFFFFu) + (acc[rr][3] >> 16));
    *(ushort4*)&Y[(size_t)(m0 + ty * 4 + rr) * N + n0 + tx * 4] = v;
  }
}

// --------------------------- scan (ulinear accum + ucompare) + next-layer prep
template<int NOUT>
__global__ __launch_bounds__(256) void k_scan(
    const uint16_t* __restrict__ ycnt, const float* __restrict__ bias,
    const float* __restrict__ rngf, float offset,
    uint16_t* __restrict__ Un, uint32_t* __restrict__ xmn)
{
  __shared__ float rs[256];
  int tid = threadIdx.x;
  rs[tid] = rngf[tid];
  __syncthreads();
  int g = blockIdx.x * 256 + tid;
  int o = g & (NOUT - 1);
  int b = g / NOUT;
  float bo = bias[o];
  float in_acc = 0.f, out_acc = 0.f, c = 0.f;
  int cum = 0;
  constexpr int WPR = NOUT / 32;
  uint16_t cur[8];
  #pragma unroll
  for (int j = 0; j < 8; ++j) cur[j] = ycnt[(size_t)(j * NB + b) * NOUT + o];
  for (int t0 = 0; t0 < TSTEPS; t0 += 8) {
    uint16_t nxt[8];
    #pragma unroll
    for (int j = 0; j < 8; ++j) {
      int tq = t0 + 8 + j; if (tq > 255) tq = 255;
      nxt[j] = ycnt[(size_t)(tq * NB + b) * NOUT + o];
    }
    #pragma unroll
    for (int j = 0; j < 8; ++j) {
      int t = t0 + j;
      float y = (float)cur[j] + ((bo > rs[t]) ? 1.f : 0.f);
      in_acc += y - offset;
      float outb = (in_acc > out_acc) ? 1.f : 0.f;
      out_acc += outb;
      float a = (c < 0.f) ? 1.f : outb;   // unary ReLU
      c += 2.f * a - 1.f;
      int xi = (int)a;
      int idx = xi ? cum : (t - cum);
      uint32_t p = perm8(idx);
      Un[(size_t)(t * NB + b) * NOUT + o] = (uint16_t)(xi ? p : (510u - p));
      cum += xi;
      unsigned long long bal = __ballot(xi == 0);
      if ((o & 63) == 0) {
        xmn[(size_t)(t * NB + b) * WPR + (o >> 5)]     = (uint32_t)bal;
        xmn[(size_t)(t * NB + b) * WPR + (o >> 5) + 1] = (uint32_t)(bal >> 32);
      }
    }
    #pragma unroll
    for (int j = 0; j < 8; ++j) cur[j] = nxt[j];
  }
}

// ------------------------------------------------------------ layer 3 (OUT=10)
__global__ __launch_bounds__(256) void k_l3(
    const uint16_t* __restrict__ U3, const uint32_t* __restrict__ xm3,
    const uint16_t* __restrict__ T3, uint16_t* __restrict__ y3)
{
  __shared__ uint32_t T3s[128][16];    // [kpair][o]
  __shared__ uint32_t Us3[16][132];    // [m][kpair]
  __shared__ uint32_t Fs3[16][132];
  int tid = threadIdx.x;
  int m0 = blockIdx.x * 16;
  for (int j = tid; j < 128 * 16; j += 256) {
    int kp = j >> 4, o2 = j & 15;
    T3s[kp][o2] = (o2 < 10) ? *(const uint32_t*)(T3 + o2 * 256 + 2 * kp) : 0u;
  }
  {
    int mr = tid >> 4, ch = tid & 15;
    const uint4* su = (const uint4*)(U3 + (size_t)(m0 + mr) * 256 + ch * 16);
    uint4 a0 = su[0], a1 = su[1];
    *(uint4*)&Us3[mr][ch * 8]     = a0;
    *(uint4*)&Us3[mr][ch * 8 + 4] = a1;
    uint32_t w = xm3[(size_t)(m0 + mr) * 8 + (ch >> 1)] >> ((ch & 1) * 16);
    uint32_t fw[8];
    #pragma unroll
    for (int q = 0; q < 8; ++q) {
      uint32_t b2 = w >> (2 * q);
      fw[q] = ((b2 & 1u) * 0x1FFu) | (((b2 >> 1) & 1u) * 0x01FF0000u);
    }
    *(uint4*)&Fs3[mr][ch * 8]     = make_uint4(fw[0], fw[1], fw[2], fw[3]);
    *(uint4*)&Fs3[mr][ch * 8 + 4] = make_uint4(fw[4], fw[5], fw[6], fw[7]);
  }
  __syncthreads();
  int mr = tid >> 4, o = tid & 15;
  uint32_t acc = 0;
  #pragma unroll 8
  for (int kp = 0; kp < 128; ++kp) {
    uint32_t t2 = T3s[kp][o];
    uint32_t u2 = Us3[mr][kp];
    uint32_t f2 = Fs3[mr][kp];
    qstep(acc, t2, f2, u2);
  }
  if (o < 10) y3[(size_t)(m0 + mr) * 16 + o] = (uint16_t)((acc & 0xFFFFu) + (acc >> 16));
}

// ------------------------------------- layer-3 scan + log_softmax (fused)
__global__ __launch_bounds__(256) void k_scan3sm(
    const uint16_t* __restrict__ y3, const float* __restrict__ b3,
    const float* __restrict__ pred, const float* __restrict__ rngf,
    float* __restrict__ out)
{
  __shared__ float rs[256];
  int tid = threadIdx.x;
  rs[tid] = rngf[tid];
  __syncthreads();
  int b = tid >> 4, o = tid & 15;
  bool act = (o < 10);
  float bo = act ? b3[o] : 0.f;
  float pr = act ? pred[b * 10 + o] : 0.f;
  float in_acc = 0.f, out_acc = 0.f;
  for (int t0 = 0; t0 < TSTEPS; t0 += 8) {
    uint16_t yv[8];
    #pragma unroll
    for (int j = 0; j < 8; ++j) yv[j] = y3[(size_t)((t0 + j) * NB + b) * 16 + o];
    #pragma unroll
    for (int j = 0; j < 8; ++j) {
      int t = t0 + j;
      float y = (float)yv[j] + ((bo > rs[t]) ? 1.f : 0.f);
      in_acc += y - 127.5f;
      float ob = (in_acc > out_acc) ? 1.f : 0.f;
      out_acc += ob;
      float z = act ? (2.f * ob - 1.f - pr) : -1e30f;
      float mx = z;
      #pragma unroll
      for (int w = 1; w < 16; w <<= 1) mx = fmaxf(mx, __shfl_xor(mx, w));
      float e = expf(z - mx);
      float s = e;
      #pragma unroll
      for (int w = 1; w < 16; w <<= 1) s += __shfl_xor(s, w);
      if (act) out[(size_t)(t * NB + b) * 10 + o] = z - mx - logf(s);
    }
  }
}

// ---------------------------------------------------------------------------
extern "C" void kernel_launch(void* const* d_in, const int* in_sizes, int n_in,
                              void* d_out, int out_size, void* d_ws, size_t ws_size,
                              hipStream_t stream) {
  (void)in_sizes; (void)n_in; (void)out_size; (void)ws_size;
  const float* w1   = (const float*)d_in[0];
  const float* b1   = (const float*)d_in[1];
  const float* w2   = (const float*)d_in[2];
  const float* b2   = (const float*)d_in[3];
  const float* w3   = (const float*)d_in[4];
  const float* b3   = (const float*)d_in[5];
  const float* pred = (const float*)d_in[6];
  const int*   x    = (const int*)d_in[7];
  float* out = (float*)d_out;
  uint8_t* W = (uint8_t*)d_ws;

  float*    rngf = (float*)   (W + 0);          //   1 KB
  uint16_t* T3   = (uint16_t*)(W + 4096);       //   8 KB (5120 used)
  uint16_t* T2   = (uint16_t*)(W + 16384);      // 256 KB
  uint16_t* T1   = (uint16_t*)(W + 278528);     //   1 MB
  uint16_t* chks = (uint16_t*)(W + 1327104);    // 256 KB
  uint16_t* U1   = (uint16_t*)(W + 1589248);    //   8 MB  [dead after bingemm1]
  uint32_t* xm1  = (uint32_t*)(W + 9977856);    // 512 KB
  uint16_t* Y1   = (uint16_t*)(W + 10502144);   //   4 MB  [dead after scan1]
  uint16_t* U2   = (uint16_t*)(W + 14696448);   //   4 MB
  uint32_t* xm2  = (uint32_t*)(W + 18890752);   // 256 KB
  uint16_t* Y2   = (uint16_t*)(W + 19152896);   //   2 MB
  // reuse of the (dead) U1 region:
  uint16_t* U3   = (uint16_t*)(W + 1589248);    //   2 MB
  uint32_t* xm3  = (uint32_t*)(W + 3686400);    // 128 KB
  uint16_t* Y3   = (uint16_t*)(W + 3817472);    // 128 KB
  // total footprint: 21,250,048 bytes

  hipLaunchKernelGGL(k_rng,    dim3(1),    dim3(256), 0, stream, rngf);
  hipLaunchKernelGGL(k_wrank,  dim3(2048), dim3(256), 0, stream, w1, T1, 512 * 1024);
  hipLaunchKernelGGL(k_wrank,  dim3(512),  dim3(256), 0, stream, w2, T2, 256 * 512);
  hipLaunchKernelGGL(k_wrank,  dim3(10),   dim3(256), 0, stream, w3, T3, 10 * 256);
  hipLaunchKernelGGL(k_chunks, dim3(512),  dim3(256), 0, stream, x, chks);
  hipLaunchKernelGGL(k_prep1,  dim3(512),  dim3(256), 0, stream, x, chks, U1, xm1);
  hipLaunchKernelGGL(k_bingemm<1024>, dim3(64, 8), dim3(256), 0, stream,
                     U1, xm1, w1 ? T1 : T1, Y1, 512);
  hipLaunchKernelGGL(k_scan<512>, dim3(32), dim3(256), 0, stream,
                     Y1, b1, rngf, 511.5f, U2, xm2);
  hipLaunchKernelGGL(k_bingemm<512>, dim3(64, 4), dim3(256), 0, stream,
                     U2, xm2, T2, Y2, 256);
  hipLaunchKernelGGL(k_scan<256>, dim3(16), dim3(256), 0, stream,
                     Y2, b2, rngf, 255.5f, U3, xm3);
  hipLaunchKernelGGL(k_l3,     dim3(256), dim3(256), 0, stream, U3, xm3, T3, Y3);
  hipLaunchKernelGGL(k_scan3sm, dim3(1),  dim3(256), 0, stream, Y3, b3, pred, rngf, out);
}

// Round 4
// 278.325 us; speedup vs baseline: 2.1867x; 1.4843x over previous
//
#include <hip/hip_runtime.h>
#include <stdint.h>

#define TSTEPS 256
#define NB 16
#define NM (TSTEPS*NB)   // 4096

typedef short s16x2 __attribute__((ext_vector_type(2)));

// perm(i) = bitrev8(gray(i)) : the Sobol value rng[i] = 2*perm(i)/256 - 1
__device__ __forceinline__ uint32_t perm8(int i) {
  uint32_t g = (uint32_t)(i ^ (i >> 1));
  return __brev(g) >> 24;
}

// packed compare-count step, per u16 half h:
//   tmp = t ^ f   (f = 0 for x=1, 0x1FF for x=0 -> 511-t)
//   d = u - tmp (i16); s = d >> 15 (0/-1, -1 iff pred true); acc -= s
__device__ __forceinline__ void qstep(uint32_t& acc, uint32_t t2, uint32_t f2,
                                      uint32_t u2) {
  uint32_t tf = t2 ^ f2;
  s16x2 d = __builtin_bit_cast(s16x2, u2) - __builtin_bit_cast(s16x2, tf);
  s16x2 s = d >> 15;
  acc = __builtin_bit_cast(uint32_t,
        (s16x2)(__builtin_bit_cast(s16x2, acc) - s));
}

__device__ __forceinline__ uint32_t pkadd16(uint32_t a, uint32_t b) {
  return __builtin_bit_cast(uint32_t,
        (s16x2)(__builtin_bit_cast(s16x2, a) + __builtin_bit_cast(s16x2, b)));
}

__device__ __forceinline__ int rank256(float w) {
  double v = 128.0 * (double)w + 128.0;
  int t = (int)ceil(v);
  if (t < 0) t = 0; if (t > 256) t = 256;
  return t;
}

// ----------------- weights -> rank tables (transposed [kp][n]) + rng, fused
__global__ __launch_bounds__(256) void k_wrank_all(
    const float* __restrict__ w1, const float* __restrict__ w2,
    const float* __restrict__ w3, float* __restrict__ rngf,
    uint32_t* __restrict__ T1t, uint32_t* __restrict__ T2t,
    uint32_t* __restrict__ T3t)
{
  int bid = blockIdx.x, tid = threadIdx.x;
  if (bid < 1024) {                      // w1: [512][1024] -> T1t [512 kp][512 n]
    int e = bid * 256 + tid;             // word idx, 262144
    int n = e & 511, kp = e >> 9;
    int lo = rank256(w1[n * 1024 + 2 * kp]);
    int hi = rank256(w1[n * 1024 + 2 * kp + 1]);
    T1t[e] = (uint32_t)lo | ((uint32_t)hi << 16);
  } else if (bid < 1280) {               // w2: [256][512] -> T2t [256 kp][256 n]
    int e = (bid - 1024) * 256 + tid;    // 65536
    int n = e & 255, kp = e >> 8;
    int lo = rank256(w2[n * 512 + 2 * kp]);
    int hi = rank256(w2[n * 512 + 2 * kp + 1]);
    T2t[e] = (uint32_t)lo | ((uint32_t)hi << 16);
  } else if (bid < 1285) {               // w3: [10][256] -> T3t [128 kp][10 n]
    int e = (bid - 1280) * 256 + tid;
    if (e < 1280) {
      int n = e % 10, kp = e / 10;
      int lo = rank256(w3[n * 256 + 2 * kp]);
      int hi = rank256(w3[n * 256 + 2 * kp + 1]);
      T3t[e] = (uint32_t)lo | ((uint32_t)hi << 16);
    }
  } else {                               // rng table
    int i = tid;
    unsigned g = i ^ (i >> 1);
    double x = 0.0, sc = 0.5;
    for (int j = 0; j < 8; ++j) { if ((g >> j) & 1u) x += sc; sc *= 0.5; }
    rngf[i] = (float)(x * 2.0 - 1.0);
  }
}

// ------------------------------------------------- layer-1 prefix (2 passes)
__global__ __launch_bounds__(256) void k_chunks(const int* __restrict__ x,
                                                uint16_t* __restrict__ cs) {
  int g = blockIdx.x * 256 + threadIdx.x;       // 131072
  int i = g & 1023, b = (g >> 10) & 15, c = g >> 14;
  int s = 0, t0 = c * 32;
  for (int tt = t0; tt < t0 + 32; ++tt) s += x[((size_t)tt * NB + b) * 1024 + i];
  cs[(c * NB + b) * 1024 + i] = (uint16_t)s;
}

__global__ __launch_bounds__(256) void k_prep1(const int* __restrict__ x,
                                               const uint16_t* __restrict__ cs,
                                               uint16_t* __restrict__ V1) {
  int g = blockIdx.x * 256 + threadIdx.x;
  int i = g & 1023, b = (g >> 10) & 15, c = g >> 14;
  int cum = 0;
  for (int cc = 0; cc < c; ++cc) cum += cs[(cc * NB + b) * 1024 + i];
  int t0 = c * 32;
  for (int tt = t0; tt < t0 + 32; ++tt) {
    int m = tt * NB + b;
    int xv = x[((size_t)tt * NB + b) * 1024 + i];
    int idx = xv ? cum : (tt - cum);
    uint32_t p = perm8(idx);
    uint32_t v = (xv ? p : (510u - p)) | ((uint32_t)(xv ^ 1) << 15);
    V1[(size_t)m * 1024 + i] = (uint16_t)v;
    cum += xv;
  }
}

// --------------------------------------------- packed-rank binary GEMM
// BM=64, BN=128, 256 threads, thread tile 4m x 8n, split-K via blockIdx.z.
// V: u16 [4096][KD], v = u | (xbar<<15). Tt: u32 [KD/2][NT] t-pairs.
// Yp: u16 [SK][4096][NT] partial counts.
template<int KD, int NT>
__global__ __launch_bounds__(256, 4) void k_bingemm(
    const uint16_t* __restrict__ V, const uint32_t* __restrict__ Tt,
    uint16_t* __restrict__ Yp, int KC)
{
  __shared__ uint32_t UFs[64][66];   // [m][2*kp + {0:u2,1:f2}], stride 66 (pad)
  __shared__ uint32_t Bs[32][132];   // [kp][n], stride 132 (pad)
  const int tid = threadIdx.x;
  const int m0 = blockIdx.x * 64;
  const int n0 = blockIdx.y * 128;
  const int sk = blockIdx.z;
  const int k0 = sk * KC;
  const int tx = tid & 15;
  const int ty = tid >> 4;
  uint32_t acc[4][8] = {};
  for (int kt = 0; kt < KC; kt += 64) {
    const int kg = k0 + kt;
    { // stage V tile (64 rows x 64 k), unpack u/f, interleave
      const int row = tid >> 2, part = tid & 3;
      const uint4* src = (const uint4*)(V + (size_t)(m0 + row) * KD + kg + part * 16);
      uint4 pa = src[0], pb = src[1];
      uint32_t w[8] = {pa.x, pa.y, pa.z, pa.w, pb.x, pb.y, pb.z, pb.w};
      #pragma unroll
      for (int q = 0; q < 8; ++q) {
        uint32_t v2 = w[q];
        uint32_t u2 = v2 & 0x01FF01FFu;
        uint32_t f2 = __builtin_bit_cast(uint32_t,
              (s16x2)(__builtin_bit_cast(s16x2, v2) >> 15)) & 0x01FF01FFu;
        *(uint2*)&UFs[row][(part * 8 + q) * 2] = make_uint2(u2, f2);
      }
    }
    { // stage T tile (32 kp x 128 n) : straight copy
      const int kp8 = tid >> 3, seg = tid & 7;
      const uint4* src = (const uint4*)(Tt + ((size_t)(kg >> 1) + kp8) * NT + n0 + seg * 16);
      uint4 a = src[0], b = src[1], c = src[2], d = src[3];
      *(uint4*)&Bs[kp8][seg * 16]      = a;
      *(uint4*)&Bs[kp8][seg * 16 + 4]  = b;
      *(uint4*)&Bs[kp8][seg * 16 + 8]  = c;
      *(uint4*)&Bs[kp8][seg * 16 + 12] = d;
    }
    __syncthreads();
    #pragma unroll 2
    for (int kp = 0; kp < 32; ++kp) {
      uint4 b0 = *(const uint4*)&Bs[kp][tx * 4];
      uint4 b1 = *(const uint4*)&Bs[kp][64 + tx * 4];
      #pragma unroll
      for (int rr = 0; rr < 4; ++rr) {
        uint2 uf = *(const uint2*)&UFs[ty * 4 + rr][kp * 2];
        qstep(acc[rr][0], b0.x, uf.y, uf.x);
        qstep(acc[rr][1], b0.y, uf.y, uf.x);
        qstep(acc[rr][2], b0.z, uf.y, uf.x);
        qstep(acc[rr][3], b0.w, uf.y, uf.x);
        qstep(acc[rr][4], b1.x, uf.y, uf.x);
        qstep(acc[rr][5], b1.y, uf.y, uf.x);
        qstep(acc[rr][6], b1.z, uf.y, uf.x);
        qstep(acc[rr][7], b1.w, uf.y, uf.x);
      }
    }
    __syncthreads();
  }
  #pragma unroll
  for (int rr = 0; rr < 4; ++rr) {
    ushort4 va, vb;
    va.x = (uint16_t)((acc[rr][0] & 0xFFFFu) + (acc[rr][0] >> 16));
    va.y = (uint16_t)((acc[rr][1] & 0xFFFFu) + (acc[rr][1] >> 16));
    va.z = (uint16_t)((acc[rr][2] & 0xFFFFu) + (acc[rr][2] >> 16));
    va.w = (uint16_t)((acc[rr][3] & 0xFFFFu) + (acc[rr][3] >> 16));
    vb.x = (uint16_t)((acc[rr][4] & 0xFFFFu) + (acc[rr][4] >> 16));
    vb.y = (uint16_t)((acc[rr][5] & 0xFFFFu) + (acc[rr][5] >> 16));
    vb.z = (uint16_t)((acc[rr][6] & 0xFFFFu) + (acc[rr][6] >> 16));
    vb.w = (uint16_t)((acc[rr][7] & 0xFFFFu) + (acc[rr][7] >> 16));
    uint16_t* dst = Yp + ((size_t)sk * NM + m0 + ty * 4 + rr) * NT + n0;
    *(ushort4*)(dst + tx * 4)      = va;
    *(ushort4*)(dst + 64 + tx * 4) = vb;
  }
}

// -------------------------------------- sum split-K partials into Yp[0]
__global__ __launch_bounds__(256) void k_sumY(uint16_t* __restrict__ Yp,
                                              int nchunks, int SK,
                                              size_t pstride_u16)
{
  int i = blockIdx.x * 256 + threadIdx.x;
  if (i >= nchunks) return;
  uint4 s = ((const uint4*)Yp)[i];
  for (int sk = 1; sk < SK; ++sk) {
    uint4 t = ((const uint4*)(Yp + pstride_u16 * sk))[i];
    s.x = pkadd16(s.x, t.x); s.y = pkadd16(s.y, t.y);
    s.z = pkadd16(s.z, t.z); s.w = pkadd16(s.w, t.w);
  }
  ((uint4*)Yp)[i] = s;
}

// --------------------------- scan (ulinear accum + ucompare) -> next V
template<int NOUT>
__global__ __launch_bounds__(64) void k_scan(
    const uint16_t* __restrict__ ycnt, const float* __restrict__ bias,
    const float* __restrict__ rngf, float offset, uint16_t* __restrict__ Vn)
{
  __shared__ float rs[256];
  int tid = threadIdx.x;
  for (int j = tid; j < 256; j += 64) rs[j] = rngf[j];
  __syncthreads();
  int g = blockIdx.x * 64 + tid;
  int o = g & (NOUT - 1);
  int b = g / NOUT;
  float bo = bias[o];
  float in_acc = 0.f, out_acc = 0.f, c = 0.f;
  int cum = 0;
  uint16_t cur[8];
  #pragma unroll
  for (int j = 0; j < 8; ++j) cur[j] = ycnt[(size_t)(j * NB + b) * NOUT + o];
  for (int t0 = 0; t0 < TSTEPS; t0 += 8) {
    uint16_t nxt[8];
    #pragma unroll
    for (int j = 0; j < 8; ++j) {
      int tq = t0 + 8 + j; if (tq > 255) tq = 255;
      nxt[j] = ycnt[(size_t)(tq * NB + b) * NOUT + o];
    }
    #pragma unroll
    for (int j = 0; j < 8; ++j) {
      int t = t0 + j;
      float y = (float)cur[j] + ((bo > rs[t]) ? 1.f : 0.f);
      in_acc += y - offset;
      float outb = (in_acc > out_acc) ? 1.f : 0.f;
      out_acc += outb;
      float a = (c < 0.f) ? 1.f : outb;   // unary ReLU
      c += 2.f * a - 1.f;
      int xi = (int)a;
      int idx = xi ? cum : (t - cum);
      uint32_t p = perm8(idx);
      uint32_t v = (xi ? p : (510u - p)) | ((uint32_t)(xi ^ 1) << 15);
      Vn[(size_t)(t * NB + b) * NOUT + o] = (uint16_t)v;
      cum += xi;
    }
    #pragma unroll
    for (int j = 0; j < 8; ++j) cur[j] = nxt[j];
  }
}

// ------------------------------------------------------------ layer 3 (OUT=10)
__global__ __launch_bounds__(256) void k_l3(
    const uint16_t* __restrict__ V3, const uint32_t* __restrict__ T3t,
    uint16_t* __restrict__ y3)
{
  __shared__ uint32_t T3s[128][16];    // [kp][o]
  __shared__ uint32_t UFs3[16][258];   // [m][2*kp + {u,f}]
  int tid = threadIdx.x;
  int m0 = blockIdx.x * 16;
  for (int j = tid; j < 2048; j += 256) {
    int kp = j >> 4, o2 = j & 15;
    T3s[kp][o2] = (o2 < 10) ? T3t[kp * 10 + o2] : 0u;
  }
  { int row = tid >> 4, part = tid & 15;
    const uint4* src = (const uint4*)(V3 + (size_t)(m0 + row) * 256 + part * 16);
    uint4 pa = src[0], pb = src[1];
    uint32_t w[8] = {pa.x, pa.y, pa.z, pa.w, pb.x, pb.y, pb.z, pb.w};
    #pragma unroll
    for (int q = 0; q < 8; ++q) {
      uint32_t v2 = w[q];
      uint32_t u2 = v2 & 0x01FF01FFu;
      uint32_t f2 = __builtin_bit_cast(uint32_t,
            (s16x2)(__builtin_bit_cast(s16x2, v2) >> 15)) & 0x01FF01FFu;
      *(uint2*)&UFs3[row][(part * 8 + q) * 2] = make_uint2(u2, f2);
    }
  }
  __syncthreads();
  int mr = tid >> 4, o = tid & 15;
  uint32_t acc = 0;
  #pragma unroll 4
  for (int kp = 0; kp < 128; ++kp) {
    uint2 uf = *(const uint2*)&UFs3[mr][kp * 2];
    qstep(acc, T3s[kp][o], uf.y, uf.x);
  }
  if (o < 10)
    y3[(size_t)(m0 + mr) * 16 + o] = (uint16_t)((acc & 0xFFFFu) + (acc >> 16));
}

// ----------------------------------------------------- layer-3 scan -> z vals
__global__ __launch_bounds__(256) void k_scan3(
    const uint16_t* __restrict__ y3, const float* __restrict__ b3,
    const float* __restrict__ pred, const float* __restrict__ rngf,
    float* __restrict__ zbuf)
{
  __shared__ float rs[256];
  int tid = threadIdx.x;
  rs[tid] = rngf[tid];
  __syncthreads();
  int b = tid >> 4, o = tid & 15;
  bool act = (o < 10);
  float bo = act ? b3[o] : 0.f;
  float pr = act ? pred[b * 10 + o] : 0.f;
  float in_acc = 0.f, out_acc = 0.f;
  for (int t0 = 0; t0 < TSTEPS; t0 += 8) {
    uint16_t yv[8];
    #pragma unroll
    for (int j = 0; j < 8; ++j) yv[j] = y3[(size_t)((t0 + j) * NB + b) * 16 + o];
    #pragma unroll
    for (int j = 0; j < 8; ++j) {
      int t = t0 + j;
      float y = (float)yv[j] + ((bo > rs[t]) ? 1.f : 0.f);
      in_acc += y - 127.5f;
      float ob = (in_acc > out_acc) ? 1.f : 0.f;
      out_acc += ob;
      if (act) zbuf[(size_t)(t * NB + b) * 16 + o] = 2.f * ob - 1.f - pr;
    }
  }
}

// -------------------------------------------------------------- log_softmax
__global__ __launch_bounds__(256) void k_softmax(const float* __restrict__ zbuf,
                                                 float* __restrict__ out)
{
  int m = blockIdx.x * 256 + threadIdx.x;   // 4096
  float z[10], mx = -3e38f;
  #pragma unroll
  for (int o = 0; o < 10; ++o) { z[o] = zbuf[m * 16 + o]; mx = fmaxf(mx, z[o]); }
  float s = 0.f;
  #pragma unroll
  for (int o = 0; o < 10; ++o) s += expf(z[o] - mx);
  float ls = logf(s);
  #pragma unroll
  for (int o = 0; o < 10; ++o) out[m * 10 + o] = z[o] - mx - ls;
}

// ---------------------------------------------------------------------------
extern "C" void kernel_launch(void* const* d_in, const int* in_sizes, int n_in,
                              void* d_out, int out_size, void* d_ws, size_t ws_size,
                              hipStream_t stream) {
  (void)in_sizes; (void)n_in; (void)out_size;
  const float* w1   = (const float*)d_in[0];
  const float* b1   = (const float*)d_in[1];
  const float* w2   = (const float*)d_in[2];
  const float* b2   = (const float*)d_in[3];
  const float* w3   = (const float*)d_in[4];
  const float* b3   = (const float*)d_in[5];
  const float* pred = (const float*)d_in[6];
  const int*   x    = (const int*)d_in[7];
  float* out = (float*)d_out;
  uint8_t* W = (uint8_t*)d_ws;

  // static region
  float*    rngf = (float*)   (W + 0);          //   1 KB
  uint32_t* T1t  = (uint32_t*)(W + 4096);       //   1 MB   [512 kp][512 n]
  uint32_t* T2t  = (uint32_t*)(W + 1052672);    // 256 KB   [256 kp][256 n]
  uint32_t* T3t  = (uint32_t*)(W + 1314816);    //   8 KB   [128 kp][10 n]
  uint16_t* chks = (uint16_t*)(W + 1323008);    // 256 KB
  uint16_t* V1   = (uint16_t*)(W + 1585152);    //   8 MB  [dead after gemm1]
  uint16_t* Yp1  = (uint16_t*)(W + 9973760);    // SK1*4MB [Yp2 aliases after scan1]
  // aliases inside dead V1 region:
  uint16_t* V3   = (uint16_t*)(W + 1585152);    //   2 MB
  uint16_t* Y3   = (uint16_t*)(W + 3682304);    // 128 KB
  float*    zbuf = (float*)   (W + 3813376);    // 256 KB

  // split-K tier by available workspace
  int SK1, SK2;
  if      (ws_size >= 30945280u) { SK1 = 4; SK2 = 4; }  // peak ~29.5 MB
  else if (ws_size >= 22556672u) { SK1 = 2; SK2 = 4; }  // peak ~21.5 MB
  else                           { SK1 = 1; SK2 = 2; }  // peak ~17.5 MB
  const int KC1 = 1024 / SK1, KC2 = 512 / SK2;
  uint16_t* V2  = (uint16_t*)(W + 9973760 + (size_t)SK1 * 4194304); // 4 MB
  uint16_t* Yp2 = Yp1;   // reuses Yp1 region (dead after scan1); SK2*2MB <= SK1*4MB

  hipLaunchKernelGGL(k_wrank_all, dim3(1286), dim3(256), 0, stream,
                     w1, w2, w3, rngf, T1t, T2t, T3t);
  hipLaunchKernelGGL(k_chunks, dim3(512), dim3(256), 0, stream, x, chks);
  hipLaunchKernelGGL(k_prep1,  dim3(512), dim3(256), 0, stream, x, chks, V1);
  hipLaunchKernelGGL((k_bingemm<1024, 512>), dim3(64, 4, SK1), dim3(256), 0, stream,
                     V1, T1t, Yp1, KC1);
  if (SK1 > 1)
    hipLaunchKernelGGL(k_sumY, dim3(1024), dim3(256), 0, stream,
                       Yp1, 262144, SK1, (size_t)NM * 512);
  hipLaunchKernelGGL(k_scan<512>, dim3(128), dim3(64), 0, stream,
                     Yp1, b1, rngf, 511.5f, V2);
  hipLaunchKernelGGL((k_bingemm<512, 256>), dim3(64, 2, SK2), dim3(256), 0, stream,
                     V2, T2t, Yp2, KC2);
  if (SK2 > 1)
    hipLaunchKernelGGL(k_sumY, dim3(512), dim3(256), 0, stream,
                       Yp2, 131072, SK2, (size_t)NM * 256);
  hipLaunchKernelGGL(k_scan<256>, dim3(64), dim3(64), 0, stream,
                     Yp2, b2, rngf, 255.5f, V3);
  hipLaunchKernelGGL(k_l3,     dim3(256), dim3(256), 0, stream, V3, T3t, Y3);
  hipLaunchKernelGGL(k_scan3,  dim3(1),   dim3(256), 0, stream, Y3, b3, pred, rngf, zbuf);
  hipLaunchKernelGGL(k_softmax, dim3(16), dim3(256), 0, stream, zbuf, out);
}